// Round 9
// baseline (119.429 us; speedup 1.0000x reference)
//
#include <hip/hip_runtime.h>
#include <hip/hip_fp16.h>

// MacTensorUnit — R14: SINGLE-KERNEL fusion. Structure (R4): x3 = F(x0) with
// F = f∘f∘f a universal scalar map, tabulated as 1024 node-pair half2 LUT
// entries on [-8,8]; expansion -> LDS-LUT lerp -> gate -> sum4. |x|>8 tails
// exact-affine with slopes cP^3/cN^3.
//
// Kept: plain stores (R7), full data front-load (R9/R11), LUT_N=1024 +
//       TPB=128 (R10), BPT=8 (R12), NCHUNK=2 cross-chunk pipeline (R13).
// R14 (theory: mac at measurement floor below the 41us ws-fill; remaining
// addressable cost is the SECOND kernel launch + dependency bubble):
//  * prep kernel DELETED. Each mac block builds the 4KB LUT itself: 10 F3
//    evals/thread (~510 VALU inst) executed INSIDE the startup HBM-latency
//    bubble while its 64 data/weight loads are in flight -> mostly free.
//  * slopes computed per-thread (~15 VALU). Weights gathered directly
//    (32 scalar loads, L2-hot, issued 1400+cy before first use).
//  * barrier now drains only lgkm (LDS writes) — ZERO VMEM drain at the
//    barrier; all 64 data/weight loads stay in flight across it.
//  * identical fp32 math for LUT nodes -> absmax exactly 0.125.
// Pre-committed: dur_us down => fixed-overhead axis confirmed; flat/up =>
// revert to R13, declare measurement floor.

#define STEP2f    0.11110889f          // 0.33333^2
#define INV_2PI   0.15915494309189535f
#define LOG2E     1.4426950408889634f
#define LUT_N     1024
#define LUT_B     8.0f
#define LUT_SCALE 64.0f                // LUT_N / (2*LUT_B)
#define LUT_BIAS  512.0f               // LUT_N / 2
#define BPT       8                    // batches per chunk
#define NCHUNK    2                    // chunks per block
#define TPB       128                  // threads per block

struct MacCoef {
    float ca1, ca3, cb1, cb3;   // logistic-Phi poly, -log2e folded
    float A0r, dAr;             // angle affine, revolutions
    float V0s, dVs;             // velocity affine * STEP^2
};

__device__ __forceinline__ MacCoef make_coef(const float* angles, const float* velocity) {
    MacCoef c;
    c.ca1 = -1.5957691216f * LOG2E;
    c.ca3 = -0.0713548168f * LOG2E;
    c.cb1 = c.ca1 * 1.41421356237f;
    c.cb3 = c.ca3 * 2.82842712475f;
    c.A0r = angles[0] * INV_2PI;
    c.dAr = (angles[4] - angles[0]) * 1.25f * INV_2PI;
    c.V0s = velocity[0] * STEP2f;
    c.dVs = (velocity[4] - velocity[0]) * 1.25f * STEP2f;
    return c;
}

// one exact MAC step (R3 math: 2 exp2 + shared rcp + hw sin/cos)
__device__ __forceinline__ float mac_step(float x, const MacCoef& c) {
    float xx = x * x;
    float ua = fminf(x * fmaf(c.ca3, xx, c.ca1), 60.0f);
    float ub = fminf(x * fmaf(c.cb3, xx, c.cb1), 60.0f);
    float ea = __builtin_amdgcn_exp2f(ua);
    float eb = __builtin_amdgcn_exp2f(ub);
    float da = 1.0f + ea, db = 1.0f + eb;
    float rp = __builtin_amdgcn_rcpf(da * db);
    float sa = db * rp;                       // ngd(x)
    float sb = da * rp;                       // nerf(x)
    float r  = fmaf(c.dAr, sa, c.A0r);        // revolutions
    float v2 = fmaf(c.dVs, sb, c.V0s);
    float sn = __builtin_amdgcn_sinf(r);
    float cs = __builtin_amdgcn_cosf(r);
    return fmaf(v2, fmaf(x, sn, cs), x);
}

__device__ __forceinline__ float F3(float x, const MacCoef& c) {
    x = mac_step(x, c);
    x = mac_step(x, c);
    return mac_step(x, c);
}

// one chunk: 8 batches from registers -> lerp -> gate -> sum4 -> store
__device__ __forceinline__ void compute_chunk(
    const float rb[BPT][4],
    const float iw[2][4], const float ib[2][4],
    const float ow[2][4], const float ob[2][4],
    float slopeP, float slopeN, const __half2* lut, float* optr)
{
#pragma unroll
    for (int k = 0; k < BPT; ++k) {
        float yv[2][4], tg[2][4];
#pragma unroll
        for (int sf = 0; sf < 4; ++sf) {
            float xv = rb[k][sf];
#pragma unroll
            for (int e = 0; e < 2; ++e) {
                float x0 = fmaf(xv, iw[e][sf], ib[e][sf]);
                float xc = fminf(fmaxf(x0, -LUT_B), LUT_B);
                float fi = fmaf(xc, LUT_SCALE, LUT_BIAS);  // [0, LUT_N]
                int   j  = min((int)fi, LUT_N - 1);
                float fr = fi - (float)j;
                __half2 p = lut[j];                        // (F[j], F[j+1])
                float lo = __low2float(p), hi = __high2float(p);
                float v  = fmaf(fr, hi - lo, lo);          // interior F(x0)
                float dd = x0 - xc;                        // tails only
                float sl = x0 > 0.0f ? slopeP : slopeN;
                float y  = fmaf(dd, sl, v);
                yv[e][sf] = y;
                tg[e][sf] = fmaf(y, ow[e][sf], ob[e][sf]);
            }
        }

        // gate att = 0.5*tg/(1+|tg|)+0.5, shared rcp per pair (exact)
#pragma unroll
        for (int e = 0; e < 2; ++e) {
            float acc = 0.0f;
#pragma unroll
            for (int p = 0; p < 2; ++p) {
                float t0 = tg[e][2 * p], t1 = tg[e][2 * p + 1];
                float d0 = 1.0f + fabsf(t0);
                float d1 = 1.0f + fabsf(t1);
                float rr = __builtin_amdgcn_rcpf(d0 * d1);
                acc = fmaf(yv[e][2 * p],     fmaf(0.5f * t0, d1 * rr, 0.5f), acc);
                acc = fmaf(yv[e][2 * p + 1], fmaf(0.5f * t1, d0 * rr, 0.5f), acc);
            }
            optr[(size_t)k * 25088 + e * 49] = acc;        // L2 write-combine
        }
    }
}

// ---- the ONLY kernel: LUT build + expansion -> lerp -> gate -> sum4 -------
__global__ __launch_bounds__(TPB, 3) void mac_kernel(
    const float* __restrict__ data,
    const float* __restrict__ in_w,
    const float* __restrict__ in_b,
    const float* __restrict__ out_w,
    const float* __restrict__ out_b,
    const float* __restrict__ angles,
    const float* __restrict__ velocity,
    float* __restrict__ out)
{
    __shared__ __half2 lut[LUT_N];               // 4 KB

    const int tid = threadIdx.x;
    const int t  = blockIdx.x * TPB + tid;       // 0 .. 12543 (= 256*49)
    const int os = t % 49;
    const int c  = t / 49;                       // data channel, 0..255

    // ---- issue ALL global loads first: their latency hides the LUT build --
    const float* dptr = data + ((size_t)(blockIdx.y * BPT * NCHUNK) * 256 + c) * 196 + os;
    float*       optr = out  + (size_t)(blockIdx.y * BPT * NCHUNK) * 25088 + c * 98 + os;

    float rb0[BPT][4], rb1[BPT][4];
#pragma unroll
    for (int k = 0; k < BPT; ++k)
#pragma unroll
        for (int sf = 0; sf < 4; ++sf) rb0[k][sf] = dptr[(size_t)k * 50176 + sf * 49];

    // direct weight gathers for cc = 2c (e=0) and 2c+1 (e=1); L2-hot
    float iw[2][4], ibv[2][4], ow[2][4], obv[2][4];
    {
        const int wb = c * 392 + os;             // (2c)*196 + os
#pragma unroll
        for (int e = 0; e < 2; ++e)
#pragma unroll
            for (int sf = 0; sf < 4; ++sf) {
                int s = wb + e * 196 + sf * 49;
                iw[e][sf] = in_w[s];  ibv[e][sf] = in_b[s];
                ow[e][sf] = out_w[s]; obv[e][sf] = out_b[s];
            }
    }

    // ---- coef + tail slopes (uniform scalar work, ~25 VALU) ---------------
    MacCoef mc = make_coef(angles, velocity);
    float snp = __builtin_amdgcn_sinf(mc.A0r + mc.dAr);
    float cP  = fmaf(mc.V0s + mc.dVs, snp, 1.0f);
    float slopeP = cP * cP * cP;
    float snn = __builtin_amdgcn_sinf(mc.A0r);
    float cN  = fmaf(mc.V0s, snn, 1.0f);
    float slopeN = cN * cN * cN;

    // ---- in-block LUT build: runs UNDER the in-flight loads ---------------
    // thread owns entry groups [4t,4t+4) and [512+4t,512+4t+4): 2x5 F3 evals,
    // identical fp32 math to the old prep kernel (absmax invariant).
    {
        uint4* dst = (uint4*)lut;
#pragma unroll
        for (int g = 0; g < 2; ++g) {
            const int base = g * (LUT_N / 2) + 4 * tid;   // entry index
            float f[5];
#pragma unroll
            for (int n = 0; n < 5; ++n)
                f[n] = F3(fmaf((float)(base + n), 1.0f / LUT_SCALE, -LUT_B), mc);
            union { __half2 h[4]; uint4 u; } pk;
#pragma unroll
            for (int n = 0; n < 4; ++n)
                pk.h[n] = __halves2half2(__float2half(f[n]), __float2half(f[n + 1]));
            dst[tid + g * TPB] = pk.u;           // conflict-free b128 write
        }
    }

    __syncthreads();   // drains only lgkm; 64 global loads stay in flight

    // chunk-1 loads land under chunk-0's ~1400cy of compute
#pragma unroll
    for (int k = 0; k < BPT; ++k)
#pragma unroll
        for (int sf = 0; sf < 4; ++sf)
            rb1[k][sf] = dptr[(size_t)(BPT + k) * 50176 + sf * 49];

    compute_chunk(rb0, iw, ibv, ow, obv, slopeP, slopeN, lut, optr);
    compute_chunk(rb1, iw, ibv, ow, obv, slopeP, slopeN, lut,
                  optr + (size_t)BPT * 25088);
}

extern "C" void kernel_launch(void* const* d_in, const int* in_sizes, int n_in,
                              void* d_out, int out_size, void* d_ws, size_t ws_size,
                              hipStream_t stream) {
    const float* data   = (const float*)d_in[0];
    const float* in_w   = (const float*)d_in[1];
    const float* in_b   = (const float*)d_in[2];
    const float* out_w  = (const float*)d_in[3];
    const float* out_b  = (const float*)d_in[4];
    const float* angles = (const float*)d_in[5];
    const float* vel    = (const float*)d_in[6];
    float* out = (float*)d_out;
    (void)d_ws; (void)ws_size;                   // workspace unused in R14

    dim3 grid(12544 / TPB, 256 / (BPT * NCHUNK));    // (c,os) x batch-chunks
    mac_kernel<<<grid, TPB, 0, stream>>>(data, in_w, in_b, out_w, out_b,
                                         angles, vel, out);
}